// Round 2
// baseline (411.629 us; speedup 1.0000x reference)
//
#include <hip/hip_runtime.h>
#include <hip/hip_bf16.h>

typedef __bf16 bf16_t;
typedef __bf16 bf16x4 __attribute__((ext_vector_type(4)));
typedef __bf16 bf16x8 __attribute__((ext_vector_type(8)));
typedef float f32x4 __attribute__((ext_vector_type(4)));

typedef const __attribute__((address_space(1))) void gvoid_t;
typedef __attribute__((address_space(3))) void lvoid_t;

#define MB (1UL<<20)

__device__ __forceinline__ void gload_lds16(const void* g, void* l) {
    __builtin_amdgcn_global_load_lds((gvoid_t*)g, (lvoid_t*)l, 16, 0, 0);
}

// ---------------- cast f32 -> bf16 (vectorized, 4 elems/thread) ----------------
__global__ __launch_bounds__(256) void cast_kernel(const float* __restrict__ in,
                                                   bf16_t* __restrict__ out, int n4) {
    int i = blockIdx.x * 256 + threadIdx.x;
    if (i < n4) {
        float4 f = ((const float4*)in)[i];
        bf16x4 o;
        o[0] = (bf16_t)f.x; o[1] = (bf16_t)f.y; o[2] = (bf16_t)f.z; o[3] = (bf16_t)f.w;
        ((bf16x4*)out)[i] = o;
    }
}

// ---------------- generic BT GEMM: C[i,j] = sum_k A[i,k]*B[j,k] ----------------
// 128x128 tile, BK=32, 256 threads = 4 waves (2x2 of 64x64), mfma 16x16x32 bf16.
template<int OUT_BF16, int HAS_BIAS, int RELU, int HAS_RES, int VT_OUT>
__global__ __launch_bounds__(256)
void gemm_bt(const bf16_t* __restrict__ Ap, int lda,
             const bf16_t* __restrict__ Bp, int ldb,
             const float* __restrict__ bias,
             const float* __restrict__ res, int ldres,
             void* __restrict__ Cp, int ldc,
             int K, int tilesN)
{
    __shared__ bf16_t sA[128 * 32];
    __shared__ bf16_t sB[128 * 32];

    const int tile = blockIdx.x;
    const int tm = tile / tilesN, tn = tile % tilesN;
    const int rowBase = tm * 128, colBase = tn * 128;
    const int t = threadIdx.x;
    const int wave = t >> 6, lane = t & 63;
    const int wr = (wave >> 1) * 64, wc = (wave & 1) * 64;

    f32x4 acc[4][4] = {};

    const int e0 = t * 8;
    const int r0row = e0 >> 5, scol = e0 & 31;
    const int r1row = r0row + 64;

    for (int k0 = 0; k0 < K; k0 += 32) {
        #pragma unroll
        for (int r = 0; r < 2; ++r) {
            const int row = r ? r1row : r0row;
            const bf16_t* srcA = Ap + (long)(rowBase + row) * lda + k0 + scol;
            char* dstA = (char*)sA + r * 4096 + wave * 1024;
            gload_lds16(srcA, dstA);
            const bf16_t* srcB = Bp + (long)(colBase + row) * ldb + k0 + scol;
            char* dstB = (char*)sB + r * 4096 + wave * 1024;
            gload_lds16(srcB, dstB);
        }
        asm volatile("s_waitcnt vmcnt(0)" ::: "memory");
        __syncthreads();

        const int kf = (lane >> 4) * 8;
        const int lr = lane & 15;
        bf16x8 af[4], bfr[4];
        #pragma unroll
        for (int m = 0; m < 4; ++m) af[m] = *(const bf16x8*)&sA[(wr + m * 16 + lr) * 32 + kf];
        #pragma unroll
        for (int n = 0; n < 4; ++n) bfr[n] = *(const bf16x8*)&sB[(wc + n * 16 + lr) * 32 + kf];
        #pragma unroll
        for (int m = 0; m < 4; ++m)
            #pragma unroll
            for (int n = 0; n < 4; ++n)
                acc[m][n] = __builtin_amdgcn_mfma_f32_16x16x32_bf16(af[m], bfr[n], acc[m][n], 0, 0, 0);
        __syncthreads();
    }

    #pragma unroll
    for (int m = 0; m < 4; ++m) {
        #pragma unroll
        for (int r = 0; r < 4; ++r) {
            const int i = rowBase + wr + m * 16 + (lane >> 4) * 4 + r;
            #pragma unroll
            for (int n = 0; n < 4; ++n) {
                const int j = colBase + wc + n * 16 + (lane & 15);
                float v = acc[m][n][r];
                if constexpr (HAS_BIAS) v += bias[j];
                if constexpr (RELU) v = fmaxf(v, 0.0f);
                if constexpr (HAS_RES) v += res[(long)i * ldres + j];
                if constexpr (VT_OUT) {
                    // V projection: write transposed per head: Vt[b][h][c][m]
                    const long o = (((long)(i >> 10) * 8 + (j >> 7)) * 128 + (j & 127)) * 1024 + (i & 1023);
                    ((bf16_t*)Cp)[o] = (bf16_t)v;
                } else if constexpr (OUT_BF16) {
                    ((bf16_t*)Cp)[(long)i * ldc + j] = (bf16_t)v;
                } else {
                    ((float*)Cp)[(long)i * ldc + j] = v;
                }
            }
        }
    }
}

// ---------------- fused attention: scores + mask/scale + softmax + PV ----------------
// Block: 512 threads (8 waves), 16 Q-rows, full M=1024 in 64KB LDS.
// grid (N/16=64, B*H=32). Writes attn probs (f32) and hidden (bf16).
__global__ __launch_bounds__(512)
void fused_attn_kernel(const bf16_t* __restrict__ Qb,     // [b][n][h*128+c]
                       const bf16_t* __restrict__ Kb,     // [b][m][h*128+c]
                       const bf16_t* __restrict__ Vtb,    // [b][h][c][m]
                       const float* __restrict__ factors, // (B,N,M)
                       const float* __restrict__ weights, // (B,M)
                       const int* __restrict__ mmask,     // (B,M)
                       const int* __restrict__ amask,     // (B,1,N,M)
                       float* __restrict__ attn,          // (B,H,N,M)
                       bf16_t* __restrict__ hidb)         // [b][n][h*128+c]
{
    __shared__ float sS[16 * 1024];   // 64 KB; reused as bf16 P in phase C
    const int bh = blockIdx.y;
    const int b = bh >> 3, h = bh & 7;
    const int n0 = blockIdx.x * 16;
    const int t = threadIdx.x, wave = t >> 6, lane = t & 63;
    const int lr = lane & 15, lk = lane >> 4;
    const float scale = 0.08838834764831845f;  // 1/sqrt(128)
    const float NEGINF = -__builtin_inff();

    // hoist Q fragments (16 rows x 128) to registers: aq[kk] = A[i=lr][kk*32+lk*8..+7]
    const bf16_t* Qp = Qb + ((long)b * 1024 + n0) * 1024 + h * 128;
    bf16x8 aq[4];
    #pragma unroll
    for (int kk = 0; kk < 4; ++kk)
        aq[kk] = *(const bf16x8*)(Qp + (long)lr * 1024 + kk * 32 + lk * 8);

    const bf16_t* Kp = Kb + (long)b * 1024 * 1024 + h * 128;

    // ---- phase A: scores = scale*factor*weight*(Q@K^T), masked, -> LDS (swizzled)
    for (int mt = 0; mt < 8; ++mt) {
        const int c0 = mt * 128 + wave * 16;  // this wave's 16 m-columns
        f32x4 acc = {};
        #pragma unroll
        for (int kk = 0; kk < 4; ++kk) {
            bf16x8 bk = *(const bf16x8*)(Kp + (long)(c0 + lr) * 1024 + kk * 32 + lk * 8);
            acc = __builtin_amdgcn_mfma_f32_16x16x32_bf16(aq[kk], bk, acc, 0, 0, 0);
        }
        const int colm = c0 + lr;
        const float w = weights[b * 1024 + colm];
        const int mm = mmask[b * 1024 + colm];
        #pragma unroll
        for (int r = 0; r < 4; ++r) {
            const int row = lk * 4 + r;  // local q row 0..15
            const long fi = ((long)b * 1024 + n0 + row) * 1024 + colm;
            float s = acc[r] * scale * factors[fi] * w;
            if (mm | amask[fi]) s = NEGINF;
            sS[row * 1024 + (colm ^ ((row & 7) << 2))] = s;
        }
    }
    __syncthreads();

    // ---- phase B: row softmax; wave handles rows wave*2 .. wave*2+1
    #pragma unroll
    for (int rr = 0; rr < 2; ++rr) {
        const int row = wave * 2 + rr;
        float vals[16];
        float mx = NEGINF;
        #pragma unroll
        for (int q = 0; q < 16; ++q) {
            const int c = lane + q * 64;
            float v = sS[row * 1024 + (c ^ ((row & 7) << 2))];
            vals[q] = v; mx = fmaxf(mx, v);
        }
        #pragma unroll
        for (int off = 32; off; off >>= 1) mx = fmaxf(mx, __shfl_xor(mx, off));
        float sum = 0.f;
        #pragma unroll
        for (int q = 0; q < 16; ++q) { float e = __expf(vals[q] - mx); vals[q] = e; sum += e; }
        #pragma unroll
        for (int off = 32; off; off >>= 1) sum += __shfl_xor(sum, off);
        const float inv = 1.0f / sum;
        float* arow = attn + ((long)bh * 1024 + n0 + row) * 1024;
        #pragma unroll
        for (int q = 0; q < 16; ++q) {
            const int c = lane + q * 64;
            const float p = vals[q] * inv;
            arow[c] = p;  // coalesced f32 store
            // bf16 P into same LDS region (first half of each row), byte-swizzled
            const int byt = (row * 4096 + c * 2) ^ ((row & 7) << 4);
            *(bf16_t*)((char*)sS + byt) = (bf16_t)p;
        }
    }
    __syncthreads();

    // ---- phase C: hidden = P @ V ; wave covers out cols wave*16..+15 (of C=128)
    f32x4 o = {};
    const bf16_t* Vp = Vtb + ((long)bh * 128 + wave * 16 + lr) * 1024;
    for (int m0 = 0; m0 < 1024; m0 += 32) {
        const int k0 = m0 + lk * 8;
        const int byt = (lr * 4096 + k0 * 2) ^ ((lr & 7) << 4);
        bf16x8 pa = *(const bf16x8*)((const char*)sS + byt);
        bf16x8 vb = *(const bf16x8*)(Vp + k0);
        o = __builtin_amdgcn_mfma_f32_16x16x32_bf16(pa, vb, o, 0, 0, 0);
    }
    bf16_t* hp = hidb + ((long)b * 1024 + n0) * 1024 + h * 128 + wave * 16;
    #pragma unroll
    for (int r = 0; r < 4; ++r)
        hp[(long)(lk * 4 + r) * 1024 + lr] = (bf16_t)o[r];
}

// ---------------- LayerNorm over rows of 1024, one wave per row ----------------
template<int WRITE_BF16>
__global__ __launch_bounds__(256)
void ln_kernel(const float* __restrict__ x,
               const float* __restrict__ g,
               const float* __restrict__ bt,
               float* __restrict__ outf,
               bf16_t* __restrict__ outb)
{
    const int row = blockIdx.x * 4 + (threadIdx.x >> 6);
    const int lane = threadIdx.x & 63;
    const float* p = x + (long)row * 1024;
    float v[16];
    float s = 0.f;
    #pragma unroll
    for (int jj = 0; jj < 4; ++jj) {
        float4 f = ((const float4*)p)[lane + jj * 64];
        v[jj * 4 + 0] = f.x; v[jj * 4 + 1] = f.y; v[jj * 4 + 2] = f.z; v[jj * 4 + 3] = f.w;
        s += f.x + f.y + f.z + f.w;
    }
    #pragma unroll
    for (int off = 32; off > 0; off >>= 1) s += __shfl_xor(s, off);
    const float mu = s * (1.0f / 1024.0f);
    float q = 0.f;
    #pragma unroll
    for (int i = 0; i < 16; ++i) { float d = v[i] - mu; q += d * d; }
    #pragma unroll
    for (int off = 32; off > 0; off >>= 1) q += __shfl_xor(q, off);
    const float rstd = rsqrtf(q * (1.0f / 1024.0f) + 1e-5f);
    #pragma unroll
    for (int jj = 0; jj < 4; ++jj) {
        const int v4 = lane + jj * 64;
        float4 gg = ((const float4*)g)[v4];
        float4 bb = ((const float4*)bt)[v4];
        float4 o;
        o.x = (v[jj * 4 + 0] - mu) * rstd * gg.x + bb.x;
        o.y = (v[jj * 4 + 1] - mu) * rstd * gg.y + bb.y;
        o.z = (v[jj * 4 + 2] - mu) * rstd * gg.z + bb.z;
        o.w = (v[jj * 4 + 3] - mu) * rstd * gg.w + bb.w;
        ((float4*)outf)[(long)row * 256 + v4] = o;
        if constexpr (WRITE_BF16) {
            bf16x4 ob;
            ob[0] = (bf16_t)o.x; ob[1] = (bf16_t)o.y; ob[2] = (bf16_t)o.z; ob[3] = (bf16_t)o.w;
            ((bf16x4*)outb)[(long)row * 256 + v4] = ob;
        }
    }
}

extern "C" void kernel_launch(void* const* d_in, const int* in_sizes, int n_in,
                              void* d_out, int out_size, void* d_ws, size_t ws_size,
                              hipStream_t stream)
{
    (void)in_sizes; (void)n_in; (void)out_size; (void)ws_size;
    const float* input_states     = (const float*)d_in[0];
    const float* memory_states    = (const float*)d_in[1];
    const float* memory_weights   = (const float*)d_in[2];
    const int*   memory_masks     = (const int*)d_in[3];
    const float* attention_factors= (const float*)d_in[4];
    const int*   attention_masks  = (const int*)d_in[5];
    const float* Wq = (const float*)d_in[6];
    const float* bq = (const float*)d_in[7];
    const float* Wk = (const float*)d_in[8];
    const float* bk = (const float*)d_in[9];
    const float* Wv = (const float*)d_in[10];
    const float* bv = (const float*)d_in[11];
    const float* Wo = (const float*)d_in[12];
    const float* bo = (const float*)d_in[13];
    const float* g1 = (const float*)d_in[14];
    const float* b1 = (const float*)d_in[15];
    const float* We = (const float*)d_in[16];
    const float* be = (const float*)d_in[17];
    const float* Ws = (const float*)d_in[18];
    const float* bs = (const float*)d_in[19];
    const float* g2 = (const float*)d_in[20];
    const float* b2 = (const float*)d_in[21];

    float* out0 = (float*)d_out;                         // (4,1024,1024)
    float* attn = (float*)d_out + 4L * 1024 * 1024;      // (4,8,1024,1024)

    char* ws = (char*)d_ws;
    bf16_t* Wqb  = (bf16_t*)(ws + 0 * MB);
    bf16_t* Wkb  = (bf16_t*)(ws + 2 * MB);
    bf16_t* Wvb  = (bf16_t*)(ws + 4 * MB);
    bf16_t* Wob  = (bf16_t*)(ws + 6 * MB);
    bf16_t* Web  = (bf16_t*)(ws + 8 * MB);
    bf16_t* Wsb  = (bf16_t*)(ws + 12 * MB);
    bf16_t* inb  = (bf16_t*)(ws + 16 * MB);
    bf16_t* memb = (bf16_t*)(ws + 24 * MB);
    bf16_t* Qb   = (bf16_t*)(ws + 32 * MB);
    bf16_t* Kb   = (bf16_t*)(ws + 40 * MB);
    bf16_t* Vtb  = (bf16_t*)(ws + 48 * MB);
    bf16_t* hidb = (bf16_t*)(ws + 56 * MB);
    float*  preLN= (float*)(ws + 64 * MB);
    float*  out1f= (float*)(ws + 80 * MB);
    bf16_t* out1b= (bf16_t*)(ws + 96 * MB);
    bf16_t* hffn = (bf16_t*)(ws + 104 * MB);

    auto cast = [&](const float* src, bf16_t* dst, long n) {
        cast_kernel<<<(int)(n / 4 / 256), 256, 0, stream>>>(src, dst, (int)(n / 4));
    };
    cast(Wq, Wqb, 1024L * 1024);
    cast(Wk, Wkb, 1024L * 1024);
    cast(Wv, Wvb, 1024L * 1024);
    cast(Wo, Wob, 1024L * 1024);
    cast(We, Web, 2048L * 1024);
    cast(Ws, Wsb, 1024L * 2048);
    cast(input_states, inb, 4096L * 1024);
    cast(memory_states, memb, 4096L * 1024);

    // Q = in @ Wq^T + bq (bf16 out)
    gemm_bt<1,1,0,0,0><<<dim3(256), 256, 0, stream>>>(
        inb, 1024, Wqb, 1024, bq, nullptr, 0, Qb, 1024, 1024, 8);
    // K = mem @ Wk^T + bk
    gemm_bt<1,1,0,0,0><<<dim3(256), 256, 0, stream>>>(
        memb, 1024, Wkb, 1024, bk, nullptr, 0, Kb, 1024, 1024, 8);
    // V = mem @ Wv^T + bv, written transposed per head Vt[b,h,c,m]
    gemm_bt<1,1,0,0,1><<<dim3(256), 256, 0, stream>>>(
        memb, 1024, Wvb, 1024, bv, nullptr, 0, Vtb, 1024, 1024, 8);
    // fused: scores + mask/scale + softmax -> attn(d_out) ; P@V -> hidb
    fused_attn_kernel<<<dim3(64, 32), 512, 0, stream>>>(
        Qb, Kb, Vtb, attention_factors, memory_weights, memory_masks,
        attention_masks, attn, hidb);
    // preLN1 = hidden @ Wo^T + bo + input_states
    gemm_bt<0,1,0,1,0><<<dim3(256), 256, 0, stream>>>(
        hidb, 1024, Wob, 1024, bo, input_states, 1024, preLN, 1024, 1024, 8);
    // out1 = LN(preLN1) -> f32 + bf16
    ln_kernel<1><<<1024, 256, 0, stream>>>(preLN, g1, b1, out1f, out1b);
    // h = relu(out1 @ We^T + be) -> bf16 (4096,2048)
    gemm_bt<1,1,1,0,0><<<dim3(512), 256, 0, stream>>>(
        out1b, 1024, Web, 1024, be, nullptr, 0, hffn, 2048, 1024, 16);
    // preLN2 = h @ Ws^T + bs + out1
    gemm_bt<0,1,0,1,0><<<dim3(256), 256, 0, stream>>>(
        hffn, 2048, Wsb, 2048, bs, out1f, 1024, preLN, 1024, 2048, 8);
    // out = LN(preLN2) -> d_out chunk 0
    ln_kernel<0><<<1024, 256, 0, stream>>>(preLN, g2, b2, out0, nullptr);
}